// Round 7
// baseline (232.033 us; speedup 1.0000x reference)
//
#include <hip/hip_runtime.h>
#include <hip/hip_cooperative_groups.h>

namespace cg = cooperative_groups;

#define Bb 8
#define Ss 50
#define Ii 20
#define Cc 64
#define Nn 4096
#define MAXM 1024
#define POSB (Ss * Ii)    // 1000
#define NBLK 256          // cooperative grid: one block per CU

typedef unsigned short ushort_t;
typedef __attribute__((ext_vector_type(8))) short short8;   // 8 bf16 = 4 VGPRs (MFMA A/B frag)
typedef __attribute__((ext_vector_type(4))) float f32x4;    // MFMA C/D frag

__device__ inline ushort_t bf16_rn(float x) {
    unsigned u = __float_as_uint(x);
    u = u + 0x7FFFu + ((u >> 16) & 1u);     // round-to-nearest-even
    return (ushort_t)(u >> 16);
}
__device__ inline float bf16_f(ushort_t h) { return __uint_as_float(((unsigned)h) << 16); }

#define MFMA(A, B, C) __builtin_amdgcn_mfma_f32_16x16x32_bf16(A, B, C, 0, 0, 0)

// One cooperative kernel, three phases separated by grid.sync():
//  A: blocks 0..7 build per-batch compact lists; blocks 8..255 proj F=E@W + hi/lo + cvec
//  B: mean gather, 1024 waves x 8 slots
//  C: MFMA scores + online softmax + combine, 512 tiles x 2 per block
__global__ __launch_bounds__(256) void fused_kernel(
    const float* __restrict__ input, const int* __restrict__ ids,
    const int* __restrict__ seqlen, const float* __restrict__ E,
    const float* __restrict__ W, const float* __restrict__ bias,
    int* __restrict__ Mcnt, int* __restrict__ slotHead, int* __restrict__ gnext,
    float* __restrict__ cvec,
    ushort_t* __restrict__ Mhi, ushort_t* __restrict__ Mlo,
    ushort_t* __restrict__ Ehi, ushort_t* __restrict__ Elo,
    ushort_t* __restrict__ Fhi, ushort_t* __restrict__ Flo,
    float* __restrict__ out) {
    cg::grid_group grid = cg::this_grid();
    __shared__ float smemf[4352];          // 17 KB, aliased per phase/role
    __shared__ int mcnt;
    int tid = threadIdx.x;
    int blk = blockIdx.x;
    int lane = tid & 63;

    // ================= Phase A =================
    if (blk < Bb) {
        // ---- build: linked lists + compact slots for batch b (LDS atomics only) ----
        int b = blk;
        int* head = (int*)smemf;           // 4096 ints
        for (int i = tid; i < Nn; i += 256) head[i] = -1;
        if (tid == 0) mcnt = 0;
        __syncthreads();
        int P = seqlen[b] * Ii;            // masked positions are exactly p < P
        for (int p = tid; p < P; p += 256) {
            int id = ids[b * POSB + p];
            gnext[b * POSB + p] = atomicExch(&head[id], p);
        }
        __syncthreads();
        for (int i = tid; i < Nn; i += 256) {
            int h = head[i];
            if (h >= 0) slotHead[b * MAXM + atomicAdd(&mcnt, 1)] = h;
        }
        __syncthreads();
        if (tid == 0) Mcnt[b] = mcnt;
    } else {
        // ---- proj: 4-row tiles of F = E @ W, strided over 248 blocks ----
        int pb = blk - Bb;                 // 0..247
        float* wlds = smemf;               // 4096 floats
        float* elds = smemf + 4096;        // 256 floats
        for (int i = tid; i < Cc * Cc; i += 256) wlds[i] = W[i];
        int nl = tid >> 6, k = tid & 63;
        for (int t = pb; t < Nn / 4; t += NBLK - Bb) {
            int n0 = t * 4;
            __syncthreads();               // first trip also covers wlds
            float ev = E[(size_t)n0 * Cc + tid];
            elds[tid] = ev;
            __syncthreads();
            float acc = 0.f;
#pragma unroll
            for (int c = 0; c < Cc; c++) acc = fmaf(elds[nl * Cc + c], wlds[c * Cc + k], acc);
            size_t o = (size_t)(n0 + nl) * Cc + k;
            ushort_t fh = bf16_rn(acc);
            Fhi[o] = fh; Flo[o] = bf16_rn(acc - bf16_f(fh));
            ushort_t eh = bf16_rn(ev);
            Ehi[o] = eh; Elo[o] = bf16_rn(ev - bf16_f(eh));
            float p = ev * bias[k];
#pragma unroll
            for (int off = 32; off; off >>= 1) p += __shfl_down(p, off);
            if (k == 0) cvec[n0 + nl] = p;
        }
    }

    __threadfence();
    grid.sync();

    // ================= Phase B: mean gather (1024 waves x 8 slots) =================
    {
        int w0 = (blk * 256 + tid) >> 6;               // 0..1023
        for (int rep = 0; rep < 8; rep++) {
            int si = w0 + 1024 * rep;                  // 0..8191
            int b = si >> 10;
            int slot = si & (MAXM - 1);
            if (slot < Mcnt[b]) {                      // wave-uniform
                int p = slotHead[b * MAXM + slot];
                float sum = 0.f; int k = 0;
                while (p >= 0) {
                    sum += input[((size_t)(b * POSB + p)) * Cc + lane];
                    k++;
                    p = gnext[b * POSB + p];
                }
                float mv = sum / (float)k;
                ushort_t h = bf16_rn(mv);
                size_t o = ((size_t)(b * MAXM + slot)) * Cc + lane;
                Mhi[o] = h;
                Mlo[o] = bf16_rn(mv - bf16_f(h));
            }
        }
    }

    __threadfence();
    grid.sync();

    // ================= Phase C: MFMA + online softmax + combine (2 tiles/block) =================
    int wave = tid >> 6;
    int kq = lane >> 4;                                // 0..3 K-subgroup / C-row group
    int rowg = kq * 4;
#pragma unroll 1
    for (int rep = 0; rep < 2; rep++) {
        int idx = rep * NBLK + blk;                    // 0..511
        int ntile = idx >> 3;
        int b = (idx + (idx >> 3) + (idx >> 8)) & 7;   // batch mix across CUs
        int n = ntile * 64 + wave * 16 + (lane & 15);

        // B-operand frags (loop-invariant): row-major [n][k], lane k-window kq*8..+8
        size_t nb = (size_t)n * Cc + kq * 8;
        short8 Eh0 = *(const short8*)(Ehi + nb), Eh1 = *(const short8*)(Ehi + nb + 32);
        short8 El0 = *(const short8*)(Elo + nb), El1 = *(const short8*)(Elo + nb + 32);
        short8 Fh0 = *(const short8*)(Fhi + nb), Fh1 = *(const short8*)(Fhi + nb + 32);
        short8 Fl0 = *(const short8*)(Flo + nb), Fl1 = *(const short8*)(Flo + nb + 32);

        int M = Mcnt[b];
        int nmt = (M + 15) >> 4;
        size_t ab = ((size_t)(b * MAXM) + (lane & 15)) * Cc + kq * 8;

        short8 Ah0 = *(const short8*)(Mhi + ab), Ah1 = *(const short8*)(Mhi + ab + 32);
        short8 Al0 = *(const short8*)(Mlo + ab), Al1 = *(const short8*)(Mlo + ab + 32);

        float m0 = -1e30f, l = 0.f, av = 0.f;

#pragma unroll 1
        for (int mt = 0; mt < nmt; mt++) {
            int mtn = (mt + 1 < nmt) ? mt + 1 : mt;
            size_t an = ab + (size_t)mtn * (16 * Cc);
            short8 Nh0 = *(const short8*)(Mhi + an), Nh1 = *(const short8*)(Mhi + an + 32);
            short8 Nl0 = *(const short8*)(Mlo + an), Nl1 = *(const short8*)(Mlo + an + 32);

            f32x4 S = {0.f, 0.f, 0.f, 0.f}, D = {0.f, 0.f, 0.f, 0.f};
            // split-bf16: hi*hi + hi*lo + lo*hi (error ~2^-18 rel)
            S = MFMA(Ah0, Eh0, S); S = MFMA(Ah1, Eh1, S);
            S = MFMA(Ah0, El0, S); S = MFMA(Ah1, El1, S);
            S = MFMA(Al0, Eh0, S); S = MFMA(Al1, Eh1, S);
            D = MFMA(Ah0, Fh0, D); D = MFMA(Ah1, Fh1, D);
            D = MFMA(Ah0, Fl0, D); D = MFMA(Ah1, Fl1, D);
            D = MFMA(Al0, Fh0, D); D = MFMA(Al1, Fh1, D);

            int mrow = mt * 16 + rowg;
#pragma unroll
            for (int r = 0; r < 4; r++) {
                if (mrow + r < M) {
                    float s = S[r];
                    float sc = s > 0.f ? s : 0.2f * s;     // leaky_relu 0.2
                    float df = D[r];
                    float ex = __expf(-fabsf(sc - m0));
                    bool sg = sc > m0;
                    float p = sg ? 1.f : ex;
                    float al = sg ? ex : 1.f;
                    m0 = fmaxf(m0, sc);
                    l = l * al + p;
                    av = av * al + p * df;
                }
            }
            Ah0 = Nh0; Ah1 = Nh1; Al0 = Nl0; Al1 = Nl1;
        }

        // merge the 4 row-groups sharing column n (lanes xor 16, 32)
#pragma unroll
        for (int mask = 16; mask <= 32; mask <<= 1) {
            float m0b = __shfl_xor(m0, mask);
            float lb  = __shfl_xor(l,  mask);
            float avb = __shfl_xor(av, mask);
            float M0 = fmaxf(m0, m0b);
            float w1 = __expf(m0 - M0), w2 = __expf(m0b - M0);
            m0 = M0;
            l  = l * w1 + lb * w2;
            av = av * w1 + avb * w2;
        }
        if (kq == 0) out[b * Nn + n] = av / l + cvec[n];
    }
}

extern "C" void kernel_launch(void* const* d_in, const int* in_sizes, int n_in,
                              void* d_out, int out_size, void* d_ws, size_t ws_size,
                              hipStream_t stream) {
    (void)in_sizes; (void)n_in; (void)out_size; (void)ws_size;
    const float* input  = (const float*)d_in[0];
    const float* E      = (const float*)d_in[1];
    const float* W      = (const float*)d_in[2];
    const float* bias   = (const float*)d_in[3];
    const int*   ids    = (const int*)d_in[4];
    const int*   seqlen = (const int*)d_in[5];
    float* out = (float*)d_out;

    int*      Mcnt     = (int*)d_ws;                        // 16
    int*      slotHead = Mcnt + 16;                         // B*MAXM
    int*      gnext    = slotHead + Bb * MAXM;              // B*POSB
    float*    cvec     = (float*)(gnext + Bb * POSB);       // N
    ushort_t* Mhi      = (ushort_t*)(cvec + Nn);            // B*MAXM*C
    ushort_t* Mlo      = Mhi + (size_t)Bb * MAXM * Cc;
    ushort_t* Ehi      = Mlo + (size_t)Bb * MAXM * Cc;      // N*C
    ushort_t* Elo      = Ehi + (size_t)Nn * Cc;
    ushort_t* Fhi      = Elo + (size_t)Nn * Cc;
    ushort_t* Flo      = Fhi + (size_t)Nn * Cc;

    void* args[] = {
        (void*)&input, (void*)&ids, (void*)&seqlen, (void*)&E, (void*)&W, (void*)&bias,
        (void*)&Mcnt, (void*)&slotHead, (void*)&gnext, (void*)&cvec,
        (void*)&Mhi, (void*)&Mlo, (void*)&Ehi, (void*)&Elo, (void*)&Fhi, (void*)&Flo,
        (void*)&out
    };
    hipLaunchCooperativeKernel((void*)fused_kernel, dim3(NBLK), dim3(256), args, 0, stream);
}

// Round 8
// 89.982 us; speedup vs baseline: 2.5787x; 2.5787x over previous
//
#include <hip/hip_runtime.h>

#define Bb 8
#define Ss 50
#define Ii 20
#define Cc 64
#define Nn 4096
#define MAXM 1024
#define POSB (Ss * Ii)    // 1000

typedef unsigned short ushort_t;
typedef __attribute__((ext_vector_type(8))) short short8;   // 8 bf16 = 4 VGPRs (MFMA A/B frag)
typedef __attribute__((ext_vector_type(4))) float f32x4;    // MFMA C/D frag

__device__ inline ushort_t bf16_rn(float x) {
    unsigned u = __float_as_uint(x);
    u = u + 0x7FFFu + ((u >> 16) & 1u);     // round-to-nearest-even
    return (ushort_t)(u >> 16);
}
__device__ inline float bf16_f(ushort_t h) { return __uint_as_float(((unsigned)h) << 16); }

__device__ inline short8 cvthi8(float4 a, float4 b) {
    short8 r;
    r[0] = (short)bf16_rn(a.x); r[1] = (short)bf16_rn(a.y);
    r[2] = (short)bf16_rn(a.z); r[3] = (short)bf16_rn(a.w);
    r[4] = (short)bf16_rn(b.x); r[5] = (short)bf16_rn(b.y);
    r[6] = (short)bf16_rn(b.z); r[7] = (short)bf16_rn(b.w);
    return r;
}
__device__ inline short8 cvtlo8(float4 a, float4 b, short8 hi) {
    short8 r;
    r[0] = (short)bf16_rn(a.x - bf16_f((ushort_t)hi[0]));
    r[1] = (short)bf16_rn(a.y - bf16_f((ushort_t)hi[1]));
    r[2] = (short)bf16_rn(a.z - bf16_f((ushort_t)hi[2]));
    r[3] = (short)bf16_rn(a.w - bf16_f((ushort_t)hi[3]));
    r[4] = (short)bf16_rn(b.x - bf16_f((ushort_t)hi[4]));
    r[5] = (short)bf16_rn(b.y - bf16_f((ushort_t)hi[5]));
    r[6] = (short)bf16_rn(b.z - bf16_f((ushort_t)hi[6]));
    r[7] = (short)bf16_rn(b.w - bf16_f((ushort_t)hi[7]));
    return r;
}

// ---------------- K1: role-split aux ----------------
// blocks 0..7   : per-batch linked-list build + compact slot assignment (LDS atomics only)
// blocks 8..263 : F = E @ W (fp32, 16 rows each) + cvec = E @ bias
__global__ __launch_bounds__(1024) void aux_kernel(
    const float* __restrict__ input, const int* __restrict__ ids,
    const int* __restrict__ seqlen, const float* __restrict__ E,
    const float* __restrict__ W, const float* __restrict__ bias,
    int* __restrict__ Mcnt, int* __restrict__ slotHead, int* __restrict__ gnext,
    float* __restrict__ cvec, float* __restrict__ Fbuf) {
    __shared__ int smem[5120];            // 20 KB, aliased per role
    int tid = threadIdx.x;

    if (blockIdx.x < Bb) {
        int b = blockIdx.x;
        int* head = smem;                 // 4096
        __shared__ int mcnt;
        for (int i = tid; i < Nn; i += 1024) head[i] = -1;
        if (tid == 0) mcnt = 0;
        __syncthreads();
        int P = seqlen[b] * Ii;           // masked positions are exactly p < P
        if (tid < P) {
            int id = ids[b * POSB + tid];
            gnext[b * POSB + tid] = atomicExch(&head[id], tid);
        }
        __syncthreads();
        for (int i = tid; i < Nn; i += 1024) {
            int h = head[i];
            if (h >= 0) slotHead[b * MAXM + atomicAdd(&mcnt, 1)] = h;
        }
        __syncthreads();
        if (tid == 0) Mcnt[b] = mcnt;
    } else {
        int pb = blockIdx.x - Bb;
        float* wlds = (float*)smem;             // 4096 floats
        float* elds = (float*)smem + 4096;      // 1024 floats
        int n0 = pb * 16;
#pragma unroll
        for (int i = 0; i < 4; i++) wlds[tid + 1024 * i] = W[tid + 1024 * i];
        float ev = E[(size_t)n0 * Cc + tid];
        elds[tid] = ev;
        __syncthreads();
        int nl = tid >> 6, k = tid & 63;
        float acc = 0.f;
#pragma unroll
        for (int c = 0; c < Cc; c++) acc = fmaf(elds[nl * Cc + c], wlds[c * Cc + k], acc);
        Fbuf[(size_t)(n0 + nl) * Cc + k] = acc;
        float p = ev * bias[k];
#pragma unroll
        for (int off = 32; off; off >>= 1) p += __shfl_down(p, off);
        if (k == 0) cvec[n0 + nl] = p;
    }
}

// ---------------- K2: mean gather — one wave per slot, bf16-hi output only ----------------
__global__ __launch_bounds__(256) void mean_kernel(
    const float* __restrict__ input, const int* __restrict__ slotHead,
    const int* __restrict__ gnext, const int* __restrict__ Mcnt,
    ushort_t* __restrict__ Mhi) {
    int w = (blockIdx.x * 256 + threadIdx.x) >> 6;
    int lane = threadIdx.x & 63;
    int b = w >> 10;
    int slot = w & (MAXM - 1);
    if (slot >= Mcnt[b]) return;          // wave-uniform
    int p = slotHead[b * MAXM + slot];
    float sum = 0.f; int k = 0;
    while (p >= 0) {
        sum += input[((size_t)(b * POSB + p)) * Cc + lane];
        k++;
        p = gnext[b * POSB + p];
    }
    Mhi[((size_t)(b * MAXM + slot)) * Cc + lane] = bf16_rn(sum / (float)k);
}

#define MFMA(A, B, C) __builtin_amdgcn_mfma_f32_16x16x32_bf16(A, B, C, 0, 0, 0)

// ---------------- K3: MFMA scores + online softmax + combine ----------------
// block = (b, 64-n tile); 4 waves x 16 n-cols each; loop m in 16-tiles.
// S hi-only (constant-shift part cancels in softmax); D hi + F-lo (F-side error
// is fixed per n and would reach ~9e-4 without the lo term; mean-side lo averages away).
__global__ __launch_bounds__(256) void main_kernel(
    const float* __restrict__ E, const float* __restrict__ Fbuf,
    const ushort_t* __restrict__ Mhi,
    const int* __restrict__ Mcnt, const float* __restrict__ cvec,
    float* __restrict__ out) {
    int idx = blockIdx.x;
    int ntile = idx >> 3;
    int b = (idx + (idx >> 3) + (idx >> 8)) & 7;   // batch mix across CU round-robin
    int tid = threadIdx.x;
    int wave = tid >> 6, lane = tid & 63;
    int kq = lane >> 4;                            // 0..3 (K-subgroup / C-row group)
    int n = ntile * 64 + wave * 16 + (lane & 15);

    // B-operand frags: convert fp32 E/F rows inline (no reuse across blocks)
    const float4* ep = (const float4*)(E + (size_t)n * Cc + kq * 8);
    const float4* fp = (const float4*)(Fbuf + (size_t)n * Cc + kq * 8);
    float4 ea = ep[0], eb = ep[1], ec = ep[8], ed = ep[9];   // +8 float4 = +32 floats
    float4 fa = fp[0], fb = fp[1], fc = fp[8], fd = fp[9];
    short8 Eh0 = cvthi8(ea, eb), Eh1 = cvthi8(ec, ed);
    short8 Fh0 = cvthi8(fa, fb), Fh1 = cvthi8(fc, fd);
    short8 Fl0 = cvtlo8(fa, fb, Fh0), Fl1 = cvtlo8(fc, fd, Fh1);

    int M = Mcnt[b];
    int nmt = (M + 15) >> 4;
    size_t ab = ((size_t)(b * MAXM) + (lane & 15)) * Cc + kq * 8;

    // prefetch A-frags for m-tile 0
    short8 Ah0 = *(const short8*)(Mhi + ab), Ah1 = *(const short8*)(Mhi + ab + 32);

    float m0 = -1e30f, l = 0.f, av = 0.f;
    int rowg = kq * 4;

#pragma unroll 1
    for (int mt = 0; mt < nmt; mt++) {
        int mtn = (mt + 1 < nmt) ? mt + 1 : mt;
        size_t an = ab + (size_t)mtn * (16 * Cc);
        short8 Nh0 = *(const short8*)(Mhi + an), Nh1 = *(const short8*)(Mhi + an + 32);

        f32x4 S = {0.f, 0.f, 0.f, 0.f}, D = {0.f, 0.f, 0.f, 0.f};
        S = MFMA(Ah0, Eh0, S); S = MFMA(Ah1, Eh1, S);
        D = MFMA(Ah0, Fh0, D); D = MFMA(Ah1, Fh1, D);
        D = MFMA(Ah0, Fl0, D); D = MFMA(Ah1, Fl1, D);

        int mrow = mt * 16 + rowg;
#pragma unroll
        for (int r = 0; r < 4; r++) {
            if (mrow + r < M) {
                float s = S[r];
                float sc = s > 0.f ? s : 0.2f * s;     // leaky_relu 0.2
                float df = D[r];
                float ex = __expf(-fabsf(sc - m0));
                bool sg = sc > m0;
                float p = sg ? 1.f : ex;
                float al = sg ? ex : 1.f;
                m0 = fmaxf(m0, sc);
                l = l * al + p;
                av = av * al + p * df;
            }
        }
        Ah0 = Nh0; Ah1 = Nh1;
    }

    // merge the 4 row-groups sharing column n (lanes xor 16, 32)
#pragma unroll
    for (int mask = 16; mask <= 32; mask <<= 1) {
        float m0b = __shfl_xor(m0, mask);
        float lb  = __shfl_xor(l,  mask);
        float avb = __shfl_xor(av, mask);
        float M0 = fmaxf(m0, m0b);
        float w1 = __expf(m0 - M0), w2 = __expf(m0b - M0);
        m0 = M0;
        l  = l * w1 + lb * w2;
        av = av * w1 + avb * w2;
    }
    if (kq == 0) out[b * Nn + n] = av / l + cvec[n];
}

extern "C" void kernel_launch(void* const* d_in, const int* in_sizes, int n_in,
                              void* d_out, int out_size, void* d_ws, size_t ws_size,
                              hipStream_t stream) {
    (void)in_sizes; (void)n_in; (void)out_size; (void)ws_size;
    const float* input  = (const float*)d_in[0];
    const float* E      = (const float*)d_in[1];
    const float* W      = (const float*)d_in[2];
    const float* bias   = (const float*)d_in[3];
    const int*   ids    = (const int*)d_in[4];
    const int*   seqlen = (const int*)d_in[5];
    float* out = (float*)d_out;

    int*      Mcnt     = (int*)d_ws;                        // 16
    int*      slotHead = Mcnt + 16;                         // B*MAXM
    int*      gnext    = slotHead + Bb * MAXM;              // B*POSB
    float*    cvec     = (float*)(gnext + Bb * POSB);       // N
    float*    Fbuf     = cvec + Nn;                         // N*C fp32
    ushort_t* Mhi      = (ushort_t*)(Fbuf + (size_t)Nn * Cc);  // B*MAXM*C bf16

    aux_kernel <<<Bb + Nn / 16, 1024, 0, stream>>>(input, ids, seqlen, E, W, bias,
                                                   Mcnt, slotHead, gnext, cvec, Fbuf);
    mean_kernel<<<Bb * MAXM / 4, 256, 0, stream>>>(input, slotHead, gnext, Mcnt, Mhi);
    main_kernel<<<Bb * (Nn / 64), 256, 0, stream>>>(E, Fbuf, Mhi, Mcnt, cvec, out);
}